// Round 5
// baseline (494.964 us; speedup 1.0000x reference)
//
#include <hip/hip_runtime.h>
#include <hip/hip_bf16.h>
#include <stdint.h>

#define NCAT 32
#define DIN  1536
#define DMID 1024
#define NB   128
#define TT   32

#define BM 128
#define BN 64
#define BK 32
#define LDA 40   // ushort stride for A tile rows (padded, 16B-aligned, 2-way banks = free)
#define MAXG 56  // 8 residues x 7 slots; sum ceil(n_c/4) <= 56 always fits

typedef __attribute__((ext_vector_type(8))) short short8;
typedef __attribute__((ext_vector_type(4))) float f32x4;

static __device__ __forceinline__ unsigned int pk2bf(float lo, float hi) {
  unsigned short a = __builtin_bit_cast(unsigned short, __float2bfloat16(lo));
  unsigned short b = __builtin_bit_cast(unsigned short, __float2bfloat16(hi));
  return ((unsigned int)b << 16) | (unsigned int)a;
}

// Raw barrier: only LDS ops must be visible across it. Never drain vmcnt here —
// the whole point is that global loads stay in flight across K-steps.
static __device__ __forceinline__ void bar_lds() {
  asm volatile("s_waitcnt lgkmcnt(0)" ::: "memory");
  __builtin_amdgcn_s_barrier();
  asm volatile("" ::: "memory");
}

// ws int layout: [0..127] batch_list sorted by category; [128] = MAXG;
// [132 + 4s ..] = {cat, start, cnt, pad} for slot s in [0,56). cnt==0 => empty.
// Slot s runs on XCD (s % 8); same-category groups share a residue so their
// weight reads hit the same L2. hidden bf16 at byte offset 8192.
__global__ void build_groups(const int* __restrict__ cat_ids, int* __restrict__ wsi) {
  __shared__ int cats[NB];
  __shared__ int cnt[NCAT];
  __shared__ int off[NCAT];
  int t = threadIdx.x; // blockDim = 128
  cats[t] = cat_ids[t];
  __syncthreads();
  if (t < NCAT) {
    int n = 0;
    for (int b = 0; b < NB; b++) n += (cats[b] == t);
    cnt[t] = n;
  }
  __syncthreads();
  if (t == 0) {
    int acc = 0;
    for (int c = 0; c < NCAT; c++) { off[c] = acc; acc += cnt[c]; }
  }
  __syncthreads();
  if (t < NCAT) {
    int o = off[t];
    for (int b = 0; b < NB; b++)
      if (cats[b] == t) wsi[o++] = b;
  }
  if (t == 0) {
    for (int s = 0; s < MAXG; s++) {
      wsi[132 + s * 4 + 0] = 0;
      wsi[132 + s * 4 + 1] = 0;
      wsi[132 + s * 4 + 2] = 0;
    }
    int rload[8];
    for (int r = 0; r < 8; r++) rload[r] = 0;
    for (int c = 0; c < NCAT; c++) {
      int n = cnt[c];
      if (n == 0) continue;
      int o = off[c];
      int r = 0;
      for (int k = 1; k < 8; k++) if (rload[k] < rload[r]) r = k;
      for (int j = 0; j < n; j += 4) {
        if (rload[r] >= 7) {
          r = 0;
          for (int k = 1; k < 8; k++) if (rload[k] < rload[r]) r = k;
        }
        int s = r + 8 * rload[r];
        rload[r]++;
        wsi[132 + s * 4 + 0] = c;
        wsi[132 + s * 4 + 1] = o + j;
        wsi[132 + s * 4 + 2] = (n - j) < 4 ? (n - j) : 4;
      }
    }
    wsi[128] = MAXG;
  }
}

// LAYER 1: Ain = x (fp32, rows [batch*32+t][K=1536]), Out = hidden bf16, relu
// LAYER 2: Ain = hidden (bf16 [4096][1024]), Out = final fp32 [4096][1024]
// Pipeline: 3 rotating LDS bufs; ds_writes land 2 iters ahead of compute.
// B (HBM W stream): 4 reg sets, loaded 4 tiles ahead (cover ~2 iters ~ HBM lat).
// A (L2-resident x): 2 reg sets, loaded 3 tiles ahead (cover ~1.5 iters >> L2 lat).
template <int LAYER>
__global__ __launch_bounds__(256)
void mlp_gemm(const void* __restrict__ Ain, const float* __restrict__ W,
              const float* __restrict__ bias, const int* __restrict__ wsi,
              void* __restrict__ Out, int K) {
  // XCD-aware remap: 16 column-blocks of one slot land on one XCD (L2 reuse).
  const int l    = blockIdx.y * 16 + blockIdx.x;   // gridDim.x == 16
  const int xcd  = l & 7;
  const int m    = l >> 3;                          // 0..111
  const int slot = xcd + 8 * (m >> 4);              // slot % 8 == xcd
  const int cat   = wsi[132 + slot * 4 + 0];
  const int start = wsi[132 + slot * 4 + 1];
  const int cnt   = wsi[132 + slot * 4 + 2];
  if (cnt == 0) return;
  const int n0 = (m & 15) * BN;

  __shared__ unsigned short Asm[3][BM * LDA];    // 3 x 10240 B
  __shared__ unsigned short Bsm[3][4 * BN * 8];  // 3 x 4096 B   (42 KB total)

  const int tid  = threadIdx.x;
  const int lane = tid & 63;
  const int w    = tid >> 6;   // wave id 0..3

  // ---- A staging: thread -> (row = tid>>1, khalf = (tid&1)*16)
  const int arow  = tid >> 1;
  const int khalf = (tid & 1) * 16;
  const int lb    = arow >> 5;
  const int tok   = arow & 31;
  const int lbc   = lb < (cnt - 1) ? lb : (cnt - 1);
  const int batch = wsi[start + lbc];
  const long grow = (long)(batch * TT + tok);

  // ---- B staging: thread -> kc = w (k rows w*8..w*8+7), col = lane
  const float* Wcol = W + (size_t)cat * (size_t)K * 1024 + n0 + lane;

  f32x4 acc[4][2];
#pragma unroll
  for (int i = 0; i < 4; i++)
#pragma unroll
    for (int j = 0; j < 2; j++) acc[i][j] = (f32x4){0.f, 0.f, 0.f, 0.f};

  const int wm  = (w >> 1) * 64;
  const int wn  = (w & 1) * 32;
  const int kg  = lane >> 4;    // 0..3
  const int c16 = lane & 15;

  auto loadA = [&](int tile, float4 ar[4], uint4 ah[2]) {
    const int k0 = tile * BK;
    if constexpr (LAYER == 1) {
      const float* ap = (const float*)Ain + grow * (long)K + k0 + khalf;
      ar[0] = *(const float4*)(ap + 0);
      ar[1] = *(const float4*)(ap + 4);
      ar[2] = *(const float4*)(ap + 8);
      ar[3] = *(const float4*)(ap + 12);
    } else {
      const uint4* ap = (const uint4*)((const unsigned short*)Ain + grow * (long)K + k0 + khalf);
      ah[0] = ap[0];
      ah[1] = ap[1];
    }
  };
  auto storeA = [&](unsigned short* buf, const float4 ar[4], const uint4 ah[2]) {
    if constexpr (LAYER == 1) {
      uint4 aw0 = make_uint4(pk2bf(ar[0].x, ar[0].y), pk2bf(ar[0].z, ar[0].w),
                             pk2bf(ar[1].x, ar[1].y), pk2bf(ar[1].z, ar[1].w));
      uint4 aw1 = make_uint4(pk2bf(ar[2].x, ar[2].y), pk2bf(ar[2].z, ar[2].w),
                             pk2bf(ar[3].x, ar[3].y), pk2bf(ar[3].z, ar[3].w));
      *(uint4*)&buf[arow * LDA + khalf]     = aw0;
      *(uint4*)&buf[arow * LDA + khalf + 8] = aw1;
    } else {
      *(uint4*)&buf[arow * LDA + khalf]     = ah[0];
      *(uint4*)&buf[arow * LDA + khalf + 8] = ah[1];
    }
  };
  auto loadB = [&](int tile, float br[8]) {
    const float* bp = Wcol + (size_t)(tile * BK + w * 8) * 1024;
#pragma unroll
    for (int r = 0; r < 8; r++) br[r] = bp[(size_t)r * 1024];
  };
  auto storeB = [&](unsigned short* buf, const float br[8]) {
    uint4 bw = make_uint4(pk2bf(br[0], br[1]), pk2bf(br[2], br[3]),
                          pk2bf(br[4], br[5]), pk2bf(br[6], br[7]));
    *(uint4*)&buf[(w * BN + lane) * 8] = bw;
  };
  auto compute = [&](const unsigned short* Ab, const unsigned short* Bb) {
    short8 afrag[4], bfrag[2];
#pragma unroll
    for (int i = 0; i < 4; i++)
      afrag[i] = *(const short8*)&Ab[(wm + i * 16 + c16) * LDA + kg * 8];
#pragma unroll
    for (int j = 0; j < 2; j++)
      bfrag[j] = *(const short8*)&Bb[(kg * BN + wn + j * 16 + c16) * 8];
#pragma unroll
    for (int i = 0; i < 4; i++)
#pragma unroll
      for (int j = 0; j < 2; j++)
        acc[i][j] = __builtin_amdgcn_mfma_f32_16x16x32_bf16(afrag[i], bfrag[j], acc[i][j], 0, 0, 0);
  };

  // Rotating LDS buf pointers: read = *0, write = *2; rotate after each K-step.
  unsigned short *A0 = Asm[0], *A1 = Asm[1], *A2 = Asm[2];
  unsigned short *B0 = Bsm[0], *B1 = Bsm[1], *B2 = Bsm[2];

  // Static register sets (unroll-4 cycles them; no runtime-indexed arrays).
  float4 ar0[4], ar1[4]; uint4 ah0[2], ah1[2];
  float br0[8], br1[8], br2[8], br3[8];

  const int nt = K / BK;   // 48 or 32: both % 4 == 0, both >= 8

  // ---- prologue: tiles 0,1 -> LDS bufs 0,1; tile 2 in A-regs; B tiles 0..3 in regs.
  loadA(0, ar0, ah0);
  loadA(1, ar1, ah1);
  loadB(0, br0); loadB(1, br1); loadB(2, br2); loadB(3, br3);
  storeA(A0, ar0, ah0); storeB(B0, br0);
  loadA(2, ar0, ah0);
  storeA(A1, ar1, ah1); storeB(B1, br1);
  bar_lds();

  // Steady state, iter t: loadA(t+3)->ar[(t+3)&1], loadB(t+4)->br[t&3],
  // storeA(t+2)<-ar[t&1] -> buf*2, storeB(t+2)<-br[(t+2)&3] -> buf*2,
  // compute(tile t from buf*0), lds-barrier, rotate.
#define STEP(TT_, ARL, AHL, BRL, ARS, AHS, BRS)                     \
  {                                                                 \
    const int t_ = (TT_);                                           \
    const int tl3 = (t_ + 3 < nt) ? t_ + 3 : nt - 1;                \
    const int tl4 = (t_ + 4 < nt) ? t_ + 4 : nt - 1;                \
    loadA(tl3, ARL, AHL);                                           \
    loadB(tl4, BRL);                                                \
    storeA(A2, ARS, AHS);                                           \
    storeB(B2, BRS);                                                \
    compute(A0, B0);                                                \
    bar_lds();                                                      \
    unsigned short* tA = A0; A0 = A1; A1 = A2; A2 = tA;             \
    unsigned short* tB = B0; B0 = B1; B1 = B2; B2 = tB;             \
  }

  for (int t = 0; t < nt; t += 4) {
    STEP(t + 0, ar1, ah1, br0, ar0, ah0, br2)
    STEP(t + 1, ar0, ah0, br1, ar1, ah1, br3)
    STEP(t + 2, ar1, ah1, br2, ar0, ah0, br0)
    STEP(t + 3, ar0, ah0, br3, ar1, ah1, br1)
  }
#undef STEP

  // ---------- epilogue ----------
  const int rquad = (lane >> 4) * 4;
#pragma unroll
  for (int i = 0; i < 4; i++) {
#pragma unroll
    for (int j = 0; j < 2; j++) {
      int gcol = n0 + wn + j * 16 + c16;
      float bb = bias[cat * 1024 + gcol];
#pragma unroll
      for (int r = 0; r < 4; r++) {
        int lrow = wm + i * 16 + rquad + r;
        int lb2 = lrow >> 5;
        if (lb2 < cnt) {
          int b2 = wsi[start + lb2];
          long orow = (long)(b2 * TT + (lrow & 31));
          float v = acc[i][j][r] + bb;
          if constexpr (LAYER == 1) {
            v = fmaxf(v, 0.f);
            ((unsigned short*)Out)[orow * DMID + gcol] =
                __builtin_bit_cast(unsigned short, __float2bfloat16(v));
          } else {
            ((float*)Out)[orow * 1024 + gcol] = v;
          }
        }
      }
    }
  }
}

extern "C" void kernel_launch(void* const* d_in, const int* in_sizes, int n_in,
                              void* d_out, int out_size, void* d_ws, size_t ws_size,
                              hipStream_t stream) {
  const float* x       = (const float*)d_in[0];
  const int*   cat_ids = (const int*)d_in[1];
  const float* W1      = (const float*)d_in[2];
  const float* b1      = (const float*)d_in[3];
  const float* W2      = (const float*)d_in[4];
  const float* b2      = (const float*)d_in[5];
  float* out = (float*)d_out;

  int* wsi = (int*)d_ws;
  unsigned short* hidden = (unsigned short*)((char*)d_ws + 8192);

  build_groups<<<dim3(1), dim3(128), 0, stream>>>(cat_ids, wsi);
  mlp_gemm<1><<<dim3(1024 / BN, MAXG), dim3(256), 0, stream>>>(
      (const void*)x, W1, b1, wsi, (void*)hidden, DIN);
  mlp_gemm<2><<<dim3(1024 / BN, MAXG), dim3(256), 0, stream>>>(
      (const void*)hidden, W2, b2, wsi, (void*)out, DMID);
}